// Round 25
// baseline (472.009 us; speedup 1.0000x reference)
//
#include <hip/hip_runtime.h>
#include <math.h>

typedef __bf16 bf16_t;
typedef unsigned char u8;
typedef __bf16 bf16x4 __attribute__((ext_vector_type(4)));
typedef __bf16 bf16x8 __attribute__((ext_vector_type(8)));
typedef float f32x4 __attribute__((ext_vector_type(4)));
typedef long longx2 __attribute__((ext_vector_type(2)));

#define GLDS(gp, lp) __builtin_amdgcn_global_load_lds( \
    (const __attribute__((address_space(1))) void*)(gp), \
    (__attribute__((address_space(3))) void*)(lp), 16, 0, 0)

static constexpr int B_    = 2;
static constexpr int T_    = 16;
static constexpr int HW_   = 576;
static constexpr int NH_   = 16;
static constexpr int TOK_  = B_ * T_ * HW_;   // 18432
static constexpr int D_    = 1024;
static constexpr int D3_   = 3072;

// fp8 buffers use a kk-interleaved layout: within each 64B k-segment of a
// row, quarter q (16B) = [k-granule q | k-granule q+4].
__device__ __forceinline__ int kremap(int k) {
    return (k & ~63) | (((k >> 3) & 3) << 4) | (((k >> 5) & 1) << 3) | (k & 7);
}

// Shared K-loop body for bf16 GEMM variants (128x128, 2-phase dbuf, XCD swz,
// T2 swizzle both-sides).
#define GEMM_PROLOG_AND_KLOOP(AS, BS)                                         \
    const int tid  = threadIdx.x;                                             \
    const int lane = tid & 63, wid = tid >> 6;                                \
    const int wr   = wid >> 1, wc = wid & 1;                                  \
    const int l15  = lane & 15, lhi = lane >> 4;                              \
    const int cpx = gridDim.x >> 3;                                           \
    const int swz = (blockIdx.x & 7) * cpx + (blockIdx.x >> 3);               \
    const long row0 = (long)(swz / ntx) * 128;                                \
    const long col0 = (long)(swz % ntx) * 128;                                \
    const int  sr   = tid >> 2;                                               \
    const int  sc   = (((tid & 3) ^ ((sr >> 1) & 3)) * 8);                    \
    const bf16_t* Ag = A  + (row0 + sr) * (long)K + sc;                       \
    const bf16_t* Bg = BT + (col0 + sr) * (long)K + sc;                       \
    f32x4 acc[4][4] = {};                                                     \
    GLDS(Ag,                AS(0) + tid * 8);                                 \
    GLDS(Ag + 64 * (long)K, AS(0) + 2048 + tid * 8);                          \
    GLDS(Bg,                BS(0) + tid * 8);                                 \
    GLDS(Bg + 64 * (long)K, BS(0) + 2048 + tid * 8);                          \
    __syncthreads();                                                          \
    const int nt = K >> 5;                                                    \
    int cur = 0;                                                              \
    for (int t = 0; t < nt; ++t) {                                            \
        if (t + 1 < nt) {                                                     \
            const int k0 = (t + 1) << 5;                                      \
            GLDS(Ag + k0,                AS(cur ^ 1) + tid * 8);              \
            GLDS(Ag + 64 * (long)K + k0, AS(cur ^ 1) + 2048 + tid * 8);       \
            GLDS(Bg + k0,                BS(cur ^ 1) + tid * 8);              \
            GLDS(Bg + 64 * (long)K + k0, BS(cur ^ 1) + 2048 + tid * 8);       \
        }                                                                     \
        bf16x8 a[4], b[4];                                                    \
        _Pragma("unroll")                                                     \
        for (int i = 0; i < 4; i++) {                                         \
            const int Ra = wr * 64 + i * 16 + l15;                            \
            a[i] = *(const bf16x8*)(AS(cur) + Ra * 32                         \
                                    + ((lhi ^ ((Ra >> 1) & 3)) * 8));         \
        }                                                                     \
        _Pragma("unroll")                                                     \
        for (int j = 0; j < 4; j++) {                                         \
            const int Rb = wc * 64 + j * 16 + l15;                            \
            b[j] = *(const bf16x8*)(BS(cur) + Rb * 32                         \
                                    + ((lhi ^ ((Rb >> 1) & 3)) * 8));         \
        }                                                                     \
        __builtin_amdgcn_s_setprio(1);                                        \
        _Pragma("unroll")                                                     \
        for (int i = 0; i < 4; i++)                                           \
            _Pragma("unroll")                                                 \
            for (int j = 0; j < 4; j++)                                       \
                acc[i][j] = __builtin_amdgcn_mfma_f32_16x16x32_bf16(a[i], b[j], acc[i][j], 0, 0, 0); \
        __builtin_amdgcn_s_setprio(0);                                        \
        __syncthreads();                                                      \
        cur ^= 1;                                                             \
    }

// ---------------------------------------------------------------------------
// prep: x -> fp8 (kk-interleaved) + weight transposes (QKV->fp8, proj->bf16).
// ---------------------------------------------------------------------------
__global__ __launch_bounds__(256) void prep(const float* __restrict__ x,
                                            u8* __restrict__ x_f8,
                                            const float* __restrict__ wqs,
                                            u8* __restrict__ wTqs8,
                                            const float* __restrict__ wps,
                                            bf16_t* __restrict__ wTps,
                                            const float* __restrict__ wqt,
                                            u8* __restrict__ wTqt8,
                                            const float* __restrict__ wpt,
                                            bf16_t* __restrict__ wTpt)
{
    const int bid = blockIdx.x, tid = threadIdx.x;
    if (bid < 4096) {
        const long n = (long)TOK_ * D_;
        for (long i = ((long)bid * 256 + tid) * 8; i < n; i += 4096L * 256 * 8) {
            const float4 v0 = *(const float4*)(x + i);
            const float4 v1 = *(const float4*)(x + i + 4);
            int lo = __builtin_amdgcn_cvt_pk_fp8_f32(v0.x, v0.y, 0, false);
            lo = __builtin_amdgcn_cvt_pk_fp8_f32(v0.z, v0.w, lo, true);
            int hi = __builtin_amdgcn_cvt_pk_fp8_f32(v1.x, v1.y, 0, false);
            hi = __builtin_amdgcn_cvt_pk_fp8_f32(v1.z, v1.w, hi, true);
            int2 p; p.x = lo; p.y = hi;
            const long rb = i & ~1023L;
            const int  g  = (int)(i & 1023) >> 3;
            const int  pos = (g >> 3) * 64 + (g & 3) * 16 + ((g >> 2) & 1) * 8;
            *(int2*)(x_f8 + rb + pos) = p;
        }
        return;
    }
    const float* in; u8* out8 = nullptr; bf16_t* outb = nullptr; int C, b2;
    if (bid < 7168)       { in = wqs; out8 = wTqs8; C = 3072; b2 = bid - 4096; }
    else if (bid < 8192)  { in = wps; outb = wTps;  C = 1024; b2 = bid - 7168; }
    else if (bid < 11264) { in = wqt; out8 = wTqt8; C = 3072; b2 = bid - 8192; }
    else                  { in = wpt; outb = wTpt;  C = 1024; b2 = bid - 11264; }
    const int nbx = C >> 5;
    const int cb = (b2 % nbx) * 32, rb = (b2 / nbx) * 32;
    const int tx = tid & 31, ty = tid >> 5;   // 32 x 8
    __shared__ float tile[32][33];
    #pragma unroll
    for (int i = 0; i < 32; i += 8)
        tile[ty + i][tx] = in[(long)(rb + ty + i) * C + cb + tx];
    __syncthreads();
    if (out8) {
        const int kk = kremap(rb + tx);
        #pragma unroll
        for (int i = 0; i < 32; i += 8) {
            const int p = __builtin_amdgcn_cvt_pk_fp8_f32(tile[tx][ty + i], 0.f, 0, false);
            out8[(long)(cb + ty + i) * 1024 + kk] = (u8)(p & 0xff);
        }
    } else {
        #pragma unroll
        for (int i = 0; i < 32; i += 8)
            outb[(long)(cb + ty + i) * 1024 + rb + tx] = (bf16_t)tile[tx][ty + i];
    }
}

// ---------------------------------------------------------------------------
// bf16 -> fp8 convert (x1; kk-interleaved layout).
// ---------------------------------------------------------------------------
__global__ __launch_bounds__(256) void b2f8(const bf16_t* __restrict__ in,
                                            u8* __restrict__ out, long n)
{
    for (long i = ((long)blockIdx.x * 256 + threadIdx.x) * 8; i < n;
         i += (long)gridDim.x * 256 * 8) {
        bf16x8 v = *(const bf16x8*)(in + i);
        int lo = __builtin_amdgcn_cvt_pk_fp8_f32((float)v[0], (float)v[1], 0, false);
        lo = __builtin_amdgcn_cvt_pk_fp8_f32((float)v[2], (float)v[3], lo, true);
        int hi = __builtin_amdgcn_cvt_pk_fp8_f32((float)v[4], (float)v[5], 0, false);
        hi = __builtin_amdgcn_cvt_pk_fp8_f32((float)v[6], (float)v[7], hi, true);
        int2 p; p.x = lo; p.y = hi;
        const long rb = i & ~1023L;
        const int  g  = (int)(i & 1023) >> 3;
        const int  pos = (g >> 3) * 64 + (g & 3) * 16 + ((g >> 2) & 1) * 8;
        *(int2*)(out + rb + pos) = p;
    }
}

// ---------------------------------------------------------------------------
// fp8 QKV GEMM (R23-proven): 128x128, BK=64, 2-phase dbuf, paired-row swizzle.
// ---------------------------------------------------------------------------
__global__ __launch_bounds__(256) void gemm_f8(const u8* __restrict__ A,
                                               const u8* __restrict__ BT,
                                               const float* __restrict__ bias,
                                               bf16_t* __restrict__ Cb,
                                               bf16_t* __restrict__ vout,
                                               int vmode, int ntx,
                                               int M, int N, int K, int tperm)
{
    __shared__ bf16_t SHm[16384];          // 32 KB
    char* SH = (char*)SHm;
    const int tid  = threadIdx.x;
    const int lane = tid & 63, wid = tid >> 6;
    const int wr   = wid >> 1, wc = wid & 1;
    const int l15  = lane & 15, lhi = lane >> 4;
    const int cpx = gridDim.x >> 3;
    const int swz = (blockIdx.x & 7) * cpx + (blockIdx.x >> 3);
    const long row0 = (long)(swz / ntx) * 128;
    const long col0 = (long)(swz % ntx) * 128;

#define STG8(Xp, rbase, kt, dst) do {                                         \
        _Pragma("unroll")                                                     \
        for (int i_ = 0; i_ < 2; i_++) {                                      \
            const int c2_ = tid + i_ * 256;        /* 0..511 */               \
            const int p_ = c2_ >> 3, s_ = c2_ & 7;                            \
            const int sp_ = s_ ^ (p_ & 7);                                    \
            const int row_ = 2 * p_ + (sp_ >> 2), q_ = sp_ & 3;               \
            GLDS(Xp + (rbase + row_) * (long)K + (kt) * 64 + q_ * 16,         \
                 (dst) + c2_ * 16);                                           \
        }                                                                     \
    } while (0)

    f32x4 acc[4][4] = {};

    STG8(A,  row0, 0, SH);
    STG8(BT, col0, 0, SH + 16384);
    __syncthreads();

    const int NT = K >> 6;
    int cur = 0;
    for (int t = 0; t < NT; ++t) {
        if (t + 1 < NT) {
            STG8(A,  row0, t + 1, SH + (cur ^ 1) * 8192);
            STG8(BT, col0, t + 1, SH + 16384 + (cur ^ 1) * 8192);
        }

        long av[4][2], bv[4][2];
        #pragma unroll
        for (int i = 0; i < 4; i++) {
            const int Ra = wr * 64 + i * 16 + l15;
            const int pa_ = Ra >> 1;
            const int sa_ = (((Ra & 1) << 2) | lhi) ^ (pa_ & 7);
            longx2 v = *(const longx2*)(SH + cur * 8192 + pa_ * 128 + sa_ * 16);
            av[i][0] = v[0]; av[i][1] = v[1];
        }
        #pragma unroll
        for (int j = 0; j < 4; j++) {
            const int Rb = wc * 64 + j * 16 + l15;
            const int pb_ = Rb >> 1;
            const int sb_ = (((Rb & 1) << 2) | lhi) ^ (pb_ & 7);
            longx2 v = *(const longx2*)(SH + 16384 + cur * 8192 + pb_ * 128 + sb_ * 16);
            bv[j][0] = v[0]; bv[j][1] = v[1];
        }

        __builtin_amdgcn_s_setprio(1);
        #pragma unroll
        for (int i = 0; i < 4; i++)
            #pragma unroll
            for (int j = 0; j < 4; j++) {
                acc[i][j] = __builtin_amdgcn_mfma_f32_16x16x32_fp8_fp8(av[i][0], bv[j][0], acc[i][j], 0, 0, 0);
                acc[i][j] = __builtin_amdgcn_mfma_f32_16x16x32_fp8_fp8(av[i][1], bv[j][1], acc[i][j], 0, 0, 0);
            }
        __builtin_amdgcn_s_setprio(0);
        __syncthreads();
        cur ^= 1;
    }
#undef STG8

    // ---- epilogue ----
    if (!(vmode == 1 && col0 >= 2048)) {
        #pragma unroll
        for (int i = 0; i < 4; i++) {
            #pragma unroll
            for (int j = 0; j < 4; j++) {
                const long col  = col0 + wc * 64 + j * 16 + l15;
                const int  lrow0 = wr * 64 + i * 16 + lhi * 4;
                const int  lcol  = wc * 64 + j * 16 + l15;
                #pragma unroll
                for (int r = 0; r < 4; r++)
                    SHm[(lrow0 + r) * 128 + lcol] = (bf16_t)(acc[i][j][r] + bias[col]);
            }
        }
        __syncthreads();
        #pragma unroll
        for (int k2 = 0; k2 < 8; k2++) {
            const int cc   = k2 * 256 + tid;
            const int lrow = cc >> 4, lcol = (cc & 15) * 8;
            const long row = row0 + lrow;
            long srow = row;
            if (tperm) {
                const int ri  = (int)row;
                const int bb  = ri / (T_ * HW_);
                const int rem = ri - bb * (T_ * HW_);
                const int tt  = rem / HW_;
                const int hh  = rem - tt * HW_;
                srow = ((long)bb * HW_ + hh) * T_ + tt;
            }
            *(bf16x8*)(Cb + srow * (long)N + col0 + lcol) =
                *(const bf16x8*)&SHm[lrow * 128 + lcol];
        }
        return;
    }

    // vmode=1 V-block: scalar vt path
    #pragma unroll
    for (int i = 0; i < 4; i++) {
        #pragma unroll
        for (int j = 0; j < 4; j++) {
            const long col  = col0 + wc * 64 + j * 16 + l15;
            const long rowb = row0 + wr * 64 + i * 16 + lhi * 4;
            const int hh = ((int)col - 2048) >> 6, d = ((int)col - 2048) & 63;
            const int r0i = (int)rowb;
            const int bt0 = r0i / HW_, hw0 = r0i - bt0 * HW_;
            bf16x4 pk;
            #pragma unroll
            for (int r = 0; r < 4; r++) pk[r] = (bf16_t)(acc[i][j][r] + bias[col]);
            *(bf16x4*)(vout + ((long)(bt0 * 16 + hh) * 64 + d) * HW_ + hw0) = pk;
        }
    }
}

// ---------------------------------------------------------------------------
// Spatial proj GEMM (bf16): repack + fp32 residual.
// ---------------------------------------------------------------------------
__global__ __launch_bounds__(256) void gemm_bt_rpp(const bf16_t* __restrict__ A,
                                                   const bf16_t* __restrict__ BT,
                                                   const float* __restrict__ bias,
                                                   const float* __restrict__ resf,
                                                   bf16_t* __restrict__ Cb,
                                                   int ntx, int M, int N, int K)
{
    __shared__ bf16_t SHm[16384];
#define As_(b) (SHm + (b) * 4096)
#define Bs_(b) (SHm + 8192 + (b) * 4096)
    GEMM_PROLOG_AND_KLOOP(As_, Bs_)

    #pragma unroll
    for (int i = 0; i < 4; i++) {
        #pragma unroll
        for (int j = 0; j < 4; j++) {
            const long col  = col0 + wc * 64 + j * 16 + l15;
            const long rowb = row0 + wr * 64 + i * 16 + lhi * 4;
            const int  lrow0 = wr * 64 + i * 16 + lhi * 4;
            const int  lcol  = wc * 64 + j * 16 + l15;
            #pragma unroll
            for (int r = 0; r < 4; r++)
                SHm[(lrow0 + r) * 128 + lcol] =
                    (bf16_t)(acc[i][j][r] + bias[col] + resf[(rowb + r) * (long)N + col]);
        }
    }
    __syncthreads();
    #pragma unroll
    for (int k2 = 0; k2 < 8; k2++) {
        const int cc   = k2 * 256 + tid;
        const int lrow = cc >> 4, lcol = (cc & 15) * 8;
        *(bf16x8*)(Cb + (row0 + lrow) * (long)N + col0 + lcol) =
            *(const bf16x8*)&SHm[lrow * 128 + lcol];
    }
#undef As_
#undef Bs_
}

// ---------------------------------------------------------------------------
// Final proj GEMM (bf16): fp32 out, bf16 residual; two-pass fp32 repack.
// ---------------------------------------------------------------------------
__global__ __launch_bounds__(256) void gemm_bt_rpo(const bf16_t* __restrict__ A,
                                                   const bf16_t* __restrict__ BT,
                                                   const float* __restrict__ bias,
                                                   const bf16_t* __restrict__ resb,
                                                   float* __restrict__ Cf,
                                                   int ntx, int M, int N, int K)
{
    __shared__ bf16_t SHm[16384];
#define As_(b) (SHm + (b) * 4096)
#define Bs_(b) (SHm + 8192 + (b) * 4096)
    GEMM_PROLOG_AND_KLOOP(As_, Bs_)

    float* SHf = (float*)SHm;                 // 32 KB = 64 rows x 128 fp32
    #pragma unroll
    for (int half = 0; half < 2; half++) {
        if (wr == half) {
            #pragma unroll
            for (int i = 0; i < 4; i++) {
                #pragma unroll
                for (int j = 0; j < 4; j++) {
                    const long col  = col0 + wc * 64 + j * 16 + l15;
                    const long rowb = row0 + wr * 64 + i * 16 + lhi * 4;
                    const int  lrow0 = i * 16 + lhi * 4;
                    const int  lcol  = wc * 64 + j * 16 + l15;
                    #pragma unroll
                    for (int r = 0; r < 4; r++)
                        SHf[(lrow0 + r) * 128 + lcol] =
                            acc[i][j][r] + bias[col]
                            + (float)resb[(rowb + r) * (long)N + col];
                }
            }
        }
        __syncthreads();
        #pragma unroll
        for (int k2 = 0; k2 < 8; k2++) {
            const int cc   = k2 * 256 + tid;       // 0..2047 float4 chunks
            const int lrow = cc >> 5, lc4 = (cc & 31) * 4;
            *(float4*)(Cf + (row0 + half * 64 + lrow) * (long)N + col0 + lc4) =
                *(const float4*)&SHf[lrow * 128 + lc4];
        }
        __syncthreads();
    }
#undef As_
#undef Bs_
}

// ---------------------------------------------------------------------------
// Spatial attention, MFMA flash-style, 192-row Q-tiles, 1-D grid + T1 swizzle.
// exp2-fold: Q pre-scaled by 0.125*log2(e) so p = exp2(s) directly (saves a
// v_mul per exp; v_exp_f32 IS exp2 on CDNA).
// ---------------------------------------------------------------------------
__global__ __launch_bounds__(256) void attn_spatial(const bf16_t* __restrict__ qkv,
                                                    const bf16_t* __restrict__ vt,
                                                    bf16_t* __restrict__ out)
{
    __shared__ bf16_t Ks[2][64 * 64];
    __shared__ bf16_t Vts[2][64 * 64];
    __shared__ bf16_t Pws[4][16 * 72];
    const int tid = threadIdx.x, lane = tid & 63, w = tid >> 6;
    // bijective XCD swizzle: 1536 blocks, 192 per XCD, g-major groups of 3
    const int bid = blockIdx.x;
    const int wsz = (bid & 7) * 192 + (bid >> 3);
    const int qt = wsz % 3;               // 0..2
    const int g  = wsz / 3;               // 0..511
    const int h  = g & 15, bt = g >> 4;
    const long base = (long)bt * HW_;
    const int l15 = lane & 15, lhi = lane >> 4;
    const int row0 = qt * 192 + w * 16;   // + rg*64

    bf16x8 q[3][2];
    #pragma unroll
    for (int rg = 0; rg < 3; rg++) {
        #pragma unroll
        for (int kk = 0; kk < 2; kk++) {
            bf16x8 tq = *(const bf16x8*)(qkv + (base + row0 + rg * 64 + l15) * D3_
                                         + h * 64 + kk * 32 + lhi * 8);
            #pragma unroll
            for (int e = 0; e < 8; e++)
                tq[e] = (bf16_t)((float)tq[e] * 0.1803368801f);  // 0.125*log2(e)
            q[rg][kk] = tq;
        }
    }

    const bf16_t* Kg = qkv + base * D3_ + 1024 + h * 64;
    const bf16_t* Vg = vt + (long)g * (64 * 576);

#define STAGEKV(kt, bq) do {                                                  \
        _Pragma("unroll")                                                     \
        for (int i_ = 0; i_ < 2; i_++) {                                      \
            const int c_ = i_ * 256 + tid;                                    \
            const int r_ = c_ >> 3, cb_ = (c_ & 7) << 4;                      \
            const int cs_ = cb_ ^ ((r_ & 7) << 4);                            \
            GLDS(Kg + (long)((kt) * 64 + r_) * D3_ + (cs_ >> 1),              \
                 (char*)Ks[bq] + c_ * 16);                                    \
            GLDS(Vg + (long)r_ * 576 + (kt) * 64 + (cs_ >> 1),               \
                 (char*)Vts[bq] + c_ * 16);                                   \
        }                                                                     \
    } while (0)

    float lp[3][4] = {};
    f32x4 o[3][4] = {};

    STAGEKV(0, 0);

    for (int kt = 0; kt < 9; kt++) {
        const int cur = kt & 1;
        __syncthreads();
        if (kt < 8) STAGEKV(kt + 1, cur ^ 1);

        f32x4 acc[3][4] = {};
        #pragma unroll
        for (int j = 0; j < 4; j++) {
            const int key = j * 16 + l15;
            #pragma unroll
            for (int kk = 0; kk < 2; kk++) {
                const int boff = key * 128 + ((kk * 64 + lhi * 16) ^ ((key & 7) << 4));
                bf16x8 kb = *(const bf16x8*)((const char*)Ks[cur] + boff);
                #pragma unroll
                for (int rg = 0; rg < 3; rg++)
                    acc[rg][j] = __builtin_amdgcn_mfma_f32_16x16x32_bf16(q[rg][kk], kb, acc[rg][j], 0, 0, 0);
            }
        }

        #pragma unroll
        for (int rg = 0; rg < 3; rg++) {
            #pragma unroll
            for (int r = 0; r < 4; r++) {
                const float p0 = exp2f(acc[rg][0][r]);
                const float p1 = exp2f(acc[rg][1][r]);
                const float p2 = exp2f(acc[rg][2][r]);
                const float p3 = exp2f(acc[rg][3][r]);
                lp[rg][r] += (p0 + p1) + (p2 + p3);
                const int prow = (lhi * 4 + r) * 72 + l15;
                Pws[w][prow]      = (bf16_t)p0;
                Pws[w][prow + 16] = (bf16_t)p1;
                Pws[w][prow + 32] = (bf16_t)p2;
                Pws[w][prow + 48] = (bf16_t)p3;
            }
            __builtin_amdgcn_sched_barrier(0);

            bf16x8 pa[2];
            #pragma unroll
            for (int kk = 0; kk < 2; kk++)
                pa[kk] = *(const bf16x8*)&Pws[w][l15 * 72 + kk * 32 + lhi * 8];
            #pragma unroll
            for (int j = 0; j < 4; j++) {
                const int vrow = j * 16 + l15;
                #pragma unroll
                for (int kk = 0; kk < 2; kk++) {
                    const int boff = vrow * 128 + ((kk * 64 + lhi * 16) ^ ((vrow & 7) << 4));
                    bf16x8 vb = *(const bf16x8*)((const char*)Vts[cur] + boff);
                    o[rg][j] = __builtin_amdgcn_mfma_f32_16x16x32_bf16(pa[kk], vb, o[rg][j], 0, 0, 0);
                }
            }
            __builtin_amdgcn_sched_barrier(0);
        }
    }
#undef STAGEKV

    #pragma unroll
    for (int rg = 0; rg < 3; rg++) {
        #pragma unroll
        for (int r = 0; r < 4; r++) {
            float l = lp[rg][r];
            #pragma unroll
            for (int off = 1; off < 16; off <<= 1) l += __shfl_xor(l, off);
            const float inv = 1.f / l;
            const long row = base + row0 + rg * 64 + lhi * 4 + r;
            #pragma unroll
            for (int j = 0; j < 4; j++)
                out[row * (long)D_ + h * 64 + j * 16 + l15] = (bf16_t)(o[rg][j][r] * inv);
        }
    }
}

// ---------------------------------------------------------------------------
// Temporal attention, MFMA; no-max softmax; in-LDS V transpose (unchanged).
// ---------------------------------------------------------------------------
__global__ __launch_bounds__(256) void attn_temporal(const bf16_t* __restrict__ qkv_t,
                                                     bf16_t* __restrict__ out)
{
    __shared__ bf16_t tile[16 * 1026];     // 32.8 KB; reused as vtt [h*1024+d*16+t]
    __shared__ bf16_t Plds[4][16 * 24];
    const int tid = threadIdx.x, lane = tid & 63, w = tid >> 6;
    const int l15 = lane & 15, lhi = lane >> 4;
    const int bhw = blockIdx.x;            // 0..1151
    const int b = bhw / HW_, hw = bhw % HW_;
    const long base_row = (long)bhw * T_;
    const bf16_t* qrow = qkv_t + (base_row + l15) * D3_;

    #pragma unroll
    for (int it = 0; it < 8; it++) {
        const int c = it * 256 + tid;
        const int row = c >> 7, col = (c & 127) * 8;
        *(bf16x8*)&tile[row * 1026 + col] =
            *(const bf16x8*)(qkv_t + (base_row + row) * D3_ + 2048 + col);
    }
    __syncthreads();
    bf16x8 tv0[4], tv1[4];
    #pragma unroll
    for (int it = 0; it < 4; it++) {
        const int hd = it * 256 + tid;
        #pragma unroll
        for (int t = 0; t < 8; t++) tv0[it][t] = tile[t * 1026 + hd];
        #pragma unroll
        for (int t = 0; t < 8; t++) tv1[it][t] = tile[(8 + t) * 1026 + hd];
    }
    __syncthreads();
    #pragma unroll
    for (int it = 0; it < 4; it++) {
        const int hd = it * 256 + tid;
        *(bf16x8*)&tile[hd * 16]     = tv0[it];
        *(bf16x8*)&tile[hd * 16 + 8] = tv1[it];
    }
    __syncthreads();

    #pragma unroll
    for (int i = 0; i < 4; i++) {
        const int h = w * 4 + i;
        bf16x8 q0 = *(const bf16x8*)(qrow + h * 64 + lhi * 8);
        bf16x8 q1 = *(const bf16x8*)(qrow + h * 64 + 32 + lhi * 8);
        bf16x8 k0 = *(const bf16x8*)(qrow + 1024 + h * 64 + lhi * 8);
        bf16x8 k1 = *(const bf16x8*)(qrow + 1024 + h * 64 + 32 + lhi * 8);
        f32x4 acc = {};
        acc = __builtin_amdgcn_mfma_f32_16x16x32_bf16(q0, k0, acc, 0, 0, 0);
        acc = __builtin_amdgcn_mfma_f32_16x16x32_bf16(q1, k1, acc, 0, 0, 0);

        #pragma unroll
        for (int r = 0; r < 4; r++) {
            const int tq = lhi * 4 + r;
            float p = (l15 <= tq) ? __expf(acc[r] * 0.125f) : 0.f;
            float sum = p;
            #pragma unroll
            for (int off = 1; off < 16; off <<= 1) sum += __shfl_xor(sum, off);
            Plds[w][tq * 24 + l15] = (bf16_t)(p / sum);
        }
        __builtin_amdgcn_sched_barrier(0);

        bf16x8 pa = {};
        if (lhi < 2) pa = *(const bf16x8*)&Plds[w][l15 * 24 + lhi * 8];

        #pragma unroll
        for (int j = 0; j < 4; j++) {
            bf16x8 vb = {};
            if (lhi < 2)
                vb = *(const bf16x8*)&tile[h * 1024 + (j * 16 + l15) * 16 + lhi * 8];
            f32x4 o = {};
            o = __builtin_amdgcn_mfma_f32_16x16x32_bf16(pa, vb, o, 0, 0, 0);
            #pragma unroll
            for (int r = 0; r < 4; r++) {
                const int tq = lhi * 4 + r;
                out[(((long)b * T_ + tq) * HW_ + hw) * D_ + h * 64 + j * 16 + l15] = (bf16_t)o[r];
            }
        }
        __builtin_amdgcn_sched_barrier(0);
    }
}

// ---------------------------------------------------------------------------
extern "C" void kernel_launch(void* const* d_in, const int* in_sizes, int n_in,
                              void* d_out, int out_size, void* d_ws, size_t ws_size,
                              hipStream_t stream)
{
    const float* x       = (const float*)d_in[0];
    const float* ws_qkv  = (const float*)d_in[1];
    const float* bs_qkv  = (const float*)d_in[2];
    const float* ws_proj = (const float*)d_in[3];
    const float* bs_proj = (const float*)d_in[4];
    const float* wt_qkv  = (const float*)d_in[5];
    const float* bt_qkv  = (const float*)d_in[6];
    const float* wt_proj = (const float*)d_in[7];
    const float* bt_proj = (const float*)d_in[8];
    float* out = (float*)d_out;
    (void)in_sizes; (void)n_in; (void)out_size;

    // workspace layout (bytes); region2 is time-multiplexed:
    //   x_f8 (prep..QKV-s) -> att-s (attn_s..proj-s) -> x1_f8 (b2f8..QKV-t)
    //   -> att-t (attn_t..proj-o)
    char* ws = (char*)d_ws;
    bf16_t* qkv   = (bf16_t*)(ws);                  // 113,246,208
    u8*     x_f8  = (u8*)(ws + 113246208L);         // 18,874,368 (in region2)
    bf16_t* att   = (bf16_t*)(ws + 113246208L);     // 37,748,736 (region2)
    u8*     x1_f8 = (u8*)(ws + 113246208L);         // 18,874,368 (in region2)
    bf16_t* x1_bf = (bf16_t*)(ws + 150994944L);     // 37,748,736 (region3)
    bf16_t* vt    = x1_bf;                          // alias: vt dead before x1_bf
    u8*     wTqs8 = (u8*)(ws + 188743680L);         //  3,145,728
    bf16_t* wTps  = (bf16_t*)(ws + 195035136L);     //  2,097,152
    u8*     wTqt8 = (u8*)(ws + 197132288L);         //  3,145,728
    bf16_t* wTpt  = (bf16_t*)(ws + 203423744L);     //  2,097,152
    if (ws_size < 205520896UL) return;              // visible failure: out stays 0

    prep<<<12288, 256, 0, stream>>>(x, x_f8, ws_qkv, wTqs8, ws_proj, wTps,
                                    wt_qkv, wTqt8, wt_proj, wTpt);

    // ---- spatial branch ----  (fp8 QKV; V fused into vt; x1 bf16)
    gemm_f8<<<24 * 144, 256, 0, stream>>>(x_f8, wTqs8, bs_qkv,
                                          qkv, vt, 1, 24,
                                          TOK_, D3_, D_, 0);
    attn_spatial<<<1536, 256, 0, stream>>>(qkv, vt, att);
    gemm_bt_rpp<<<8 * 144, 256, 0, stream>>>(att, wTps, bs_proj, x,
                                             x1_bf, 8, TOK_, D_, D_);
    // ---- temporal branch ----  (x1 -> fp8, fp8 QKV with tperm)
    b2f8<<<4096, 256, 0, stream>>>(x1_bf, x1_f8, (long)TOK_ * D_);
    gemm_f8<<<24 * 144, 256, 0, stream>>>(x1_f8, wTqt8, bt_qkv,
                                          qkv, nullptr, 0, 24,
                                          TOK_, D3_, D_, 1);
    attn_temporal<<<1152, 256, 0, stream>>>(qkv, att);
    gemm_bt_rpo<<<8 * 144, 256, 0, stream>>>(att, wTpt, bt_proj, x1_bf,
                                             out, 8, TOK_, D_, D_);
}

// Round 26
// 449.150 us; speedup vs baseline: 1.0509x; 1.0509x over previous
//
#include <hip/hip_runtime.h>
#include <math.h>

typedef __bf16 bf16_t;
typedef unsigned char u8;
typedef __bf16 bf16x4 __attribute__((ext_vector_type(4)));
typedef __bf16 bf16x8 __attribute__((ext_vector_type(8)));
typedef float f32x4 __attribute__((ext_vector_type(4)));
typedef long longx2 __attribute__((ext_vector_type(2)));

#define GLDS(gp, lp) __builtin_amdgcn_global_load_lds( \
    (const __attribute__((address_space(1))) void*)(gp), \
    (__attribute__((address_space(3))) void*)(lp), 16, 0, 0)

static constexpr int B_    = 2;
static constexpr int T_    = 16;
static constexpr int HW_   = 576;
static constexpr int NH_   = 16;
static constexpr int TOK_  = B_ * T_ * HW_;   // 18432
static constexpr int D_    = 1024;
static constexpr int D3_   = 3072;

// raw HW exp2 (v_exp_f32 IS 2^x on CDNA) — avoids libm exp2f's precise path
__device__ __forceinline__ float hw_exp2(float x) {
    float r;
    asm volatile("v_exp_f32 %0, %1" : "=v"(r) : "v"(x));
    return r;
}

// fp8 buffers use a kk-interleaved layout: within each 64B k-segment of a
// row, quarter q (16B) = [k-granule q | k-granule q+4].
__device__ __forceinline__ int kremap(int k) {
    return (k & ~63) | (((k >> 3) & 3) << 4) | (((k >> 5) & 1) << 3) | (k & 7);
}

// Shared K-loop body for bf16 GEMM variants (128x128, 2-phase dbuf, XCD swz,
// T2 swizzle both-sides).
#define GEMM_PROLOG_AND_KLOOP(AS, BS)                                         \
    const int tid  = threadIdx.x;                                             \
    const int lane = tid & 63, wid = tid >> 6;                                \
    const int wr   = wid >> 1, wc = wid & 1;                                  \
    const int l15  = lane & 15, lhi = lane >> 4;                              \
    const int cpx = gridDim.x >> 3;                                           \
    const int swz = (blockIdx.x & 7) * cpx + (blockIdx.x >> 3);               \
    const long row0 = (long)(swz / ntx) * 128;                                \
    const long col0 = (long)(swz % ntx) * 128;                                \
    const int  sr   = tid >> 2;                                               \
    const int  sc   = (((tid & 3) ^ ((sr >> 1) & 3)) * 8);                    \
    const bf16_t* Ag = A  + (row0 + sr) * (long)K + sc;                       \
    const bf16_t* Bg = BT + (col0 + sr) * (long)K + sc;                       \
    f32x4 acc[4][4] = {};                                                     \
    GLDS(Ag,                AS(0) + tid * 8);                                 \
    GLDS(Ag + 64 * (long)K, AS(0) + 2048 + tid * 8);                          \
    GLDS(Bg,                BS(0) + tid * 8);                                 \
    GLDS(Bg + 64 * (long)K, BS(0) + 2048 + tid * 8);                          \
    __syncthreads();                                                          \
    const int nt = K >> 5;                                                    \
    int cur = 0;                                                              \
    for (int t = 0; t < nt; ++t) {                                            \
        if (t + 1 < nt) {                                                     \
            const int k0 = (t + 1) << 5;                                      \
            GLDS(Ag + k0,                AS(cur ^ 1) + tid * 8);              \
            GLDS(Ag + 64 * (long)K + k0, AS(cur ^ 1) + 2048 + tid * 8);       \
            GLDS(Bg + k0,                BS(cur ^ 1) + tid * 8);              \
            GLDS(Bg + 64 * (long)K + k0, BS(cur ^ 1) + 2048 + tid * 8);       \
        }                                                                     \
        bf16x8 a[4], b[4];                                                    \
        _Pragma("unroll")                                                     \
        for (int i = 0; i < 4; i++) {                                         \
            const int Ra = wr * 64 + i * 16 + l15;                            \
            a[i] = *(const bf16x8*)(AS(cur) + Ra * 32                         \
                                    + ((lhi ^ ((Ra >> 1) & 3)) * 8));         \
        }                                                                     \
        _Pragma("unroll")                                                     \
        for (int j = 0; j < 4; j++) {                                         \
            const int Rb = wc * 64 + j * 16 + l15;                            \
            b[j] = *(const bf16x8*)(BS(cur) + Rb * 32                         \
                                    + ((lhi ^ ((Rb >> 1) & 3)) * 8));         \
        }                                                                     \
        __builtin_amdgcn_s_setprio(1);                                        \
        _Pragma("unroll")                                                     \
        for (int i = 0; i < 4; i++)                                           \
            _Pragma("unroll")                                                 \
            for (int j = 0; j < 4; j++)                                       \
                acc[i][j] = __builtin_amdgcn_mfma_f32_16x16x32_bf16(a[i], b[j], acc[i][j], 0, 0, 0); \
        __builtin_amdgcn_s_setprio(0);                                        \
        __syncthreads();                                                      \
        cur ^= 1;                                                             \
    }

// ---------------------------------------------------------------------------
// prep: x -> fp8 (kk-interleaved) + weight transposes (QKV->fp8, proj->bf16).
// ---------------------------------------------------------------------------
__global__ __launch_bounds__(256) void prep(const float* __restrict__ x,
                                            u8* __restrict__ x_f8,
                                            const float* __restrict__ wqs,
                                            u8* __restrict__ wTqs8,
                                            const float* __restrict__ wps,
                                            bf16_t* __restrict__ wTps,
                                            const float* __restrict__ wqt,
                                            u8* __restrict__ wTqt8,
                                            const float* __restrict__ wpt,
                                            bf16_t* __restrict__ wTpt)
{
    const int bid = blockIdx.x, tid = threadIdx.x;
    if (bid < 4096) {
        const long n = (long)TOK_ * D_;
        for (long i = ((long)bid * 256 + tid) * 8; i < n; i += 4096L * 256 * 8) {
            const float4 v0 = *(const float4*)(x + i);
            const float4 v1 = *(const float4*)(x + i + 4);
            int lo = __builtin_amdgcn_cvt_pk_fp8_f32(v0.x, v0.y, 0, false);
            lo = __builtin_amdgcn_cvt_pk_fp8_f32(v0.z, v0.w, lo, true);
            int hi = __builtin_amdgcn_cvt_pk_fp8_f32(v1.x, v1.y, 0, false);
            hi = __builtin_amdgcn_cvt_pk_fp8_f32(v1.z, v1.w, hi, true);
            int2 p; p.x = lo; p.y = hi;
            const long rb = i & ~1023L;
            const int  g  = (int)(i & 1023) >> 3;
            const int  pos = (g >> 3) * 64 + (g & 3) * 16 + ((g >> 2) & 1) * 8;
            *(int2*)(x_f8 + rb + pos) = p;
        }
        return;
    }
    const float* in; u8* out8 = nullptr; bf16_t* outb = nullptr; int C, b2;
    if (bid < 7168)       { in = wqs; out8 = wTqs8; C = 3072; b2 = bid - 4096; }
    else if (bid < 8192)  { in = wps; outb = wTps;  C = 1024; b2 = bid - 7168; }
    else if (bid < 11264) { in = wqt; out8 = wTqt8; C = 3072; b2 = bid - 8192; }
    else                  { in = wpt; outb = wTpt;  C = 1024; b2 = bid - 11264; }
    const int nbx = C >> 5;
    const int cb = (b2 % nbx) * 32, rb = (b2 / nbx) * 32;
    const int tx = tid & 31, ty = tid >> 5;   // 32 x 8
    __shared__ float tile[32][33];
    #pragma unroll
    for (int i = 0; i < 32; i += 8)
        tile[ty + i][tx] = in[(long)(rb + ty + i) * C + cb + tx];
    __syncthreads();
    if (out8) {
        const int kk = kremap(rb + tx);
        #pragma unroll
        for (int i = 0; i < 32; i += 8) {
            const int p = __builtin_amdgcn_cvt_pk_fp8_f32(tile[tx][ty + i], 0.f, 0, false);
            out8[(long)(cb + ty + i) * 1024 + kk] = (u8)(p & 0xff);
        }
    } else {
        #pragma unroll
        for (int i = 0; i < 32; i += 8)
            outb[(long)(cb + ty + i) * 1024 + rb + tx] = (bf16_t)tile[tx][ty + i];
    }
}

// ---------------------------------------------------------------------------
// bf16 -> fp8 convert (x1; kk-interleaved layout).
// ---------------------------------------------------------------------------
__global__ __launch_bounds__(256) void b2f8(const bf16_t* __restrict__ in,
                                            u8* __restrict__ out, long n)
{
    for (long i = ((long)blockIdx.x * 256 + threadIdx.x) * 8; i < n;
         i += (long)gridDim.x * 256 * 8) {
        bf16x8 v = *(const bf16x8*)(in + i);
        int lo = __builtin_amdgcn_cvt_pk_fp8_f32((float)v[0], (float)v[1], 0, false);
        lo = __builtin_amdgcn_cvt_pk_fp8_f32((float)v[2], (float)v[3], lo, true);
        int hi = __builtin_amdgcn_cvt_pk_fp8_f32((float)v[4], (float)v[5], 0, false);
        hi = __builtin_amdgcn_cvt_pk_fp8_f32((float)v[6], (float)v[7], hi, true);
        int2 p; p.x = lo; p.y = hi;
        const long rb = i & ~1023L;
        const int  g  = (int)(i & 1023) >> 3;
        const int  pos = (g >> 3) * 64 + (g & 3) * 16 + ((g >> 2) & 1) * 8;
        *(int2*)(out + rb + pos) = p;
    }
}

// ---------------------------------------------------------------------------
// fp8 QKV GEMM (R23-proven): 128x128, BK=64, 2-phase dbuf, paired-row swizzle.
// ---------------------------------------------------------------------------
__global__ __launch_bounds__(256) void gemm_f8(const u8* __restrict__ A,
                                               const u8* __restrict__ BT,
                                               const float* __restrict__ bias,
                                               bf16_t* __restrict__ Cb,
                                               bf16_t* __restrict__ vout,
                                               int vmode, int ntx,
                                               int M, int N, int K, int tperm)
{
    __shared__ bf16_t SHm[16384];          // 32 KB
    char* SH = (char*)SHm;
    const int tid  = threadIdx.x;
    const int lane = tid & 63, wid = tid >> 6;
    const int wr   = wid >> 1, wc = wid & 1;
    const int l15  = lane & 15, lhi = lane >> 4;
    const int cpx = gridDim.x >> 3;
    const int swz = (blockIdx.x & 7) * cpx + (blockIdx.x >> 3);
    const long row0 = (long)(swz / ntx) * 128;
    const long col0 = (long)(swz % ntx) * 128;

#define STG8(Xp, rbase, kt, dst) do {                                         \
        _Pragma("unroll")                                                     \
        for (int i_ = 0; i_ < 2; i_++) {                                      \
            const int c2_ = tid + i_ * 256;        /* 0..511 */               \
            const int p_ = c2_ >> 3, s_ = c2_ & 7;                            \
            const int sp_ = s_ ^ (p_ & 7);                                    \
            const int row_ = 2 * p_ + (sp_ >> 2), q_ = sp_ & 3;               \
            GLDS(Xp + (rbase + row_) * (long)K + (kt) * 64 + q_ * 16,         \
                 (dst) + c2_ * 16);                                           \
        }                                                                     \
    } while (0)

    f32x4 acc[4][4] = {};

    STG8(A,  row0, 0, SH);
    STG8(BT, col0, 0, SH + 16384);
    __syncthreads();

    const int NT = K >> 6;
    int cur = 0;
    for (int t = 0; t < NT; ++t) {
        if (t + 1 < NT) {
            STG8(A,  row0, t + 1, SH + (cur ^ 1) * 8192);
            STG8(BT, col0, t + 1, SH + 16384 + (cur ^ 1) * 8192);
        }

        long av[4][2], bv[4][2];
        #pragma unroll
        for (int i = 0; i < 4; i++) {
            const int Ra = wr * 64 + i * 16 + l15;
            const int pa_ = Ra >> 1;
            const int sa_ = (((Ra & 1) << 2) | lhi) ^ (pa_ & 7);
            longx2 v = *(const longx2*)(SH + cur * 8192 + pa_ * 128 + sa_ * 16);
            av[i][0] = v[0]; av[i][1] = v[1];
        }
        #pragma unroll
        for (int j = 0; j < 4; j++) {
            const int Rb = wc * 64 + j * 16 + l15;
            const int pb_ = Rb >> 1;
            const int sb_ = (((Rb & 1) << 2) | lhi) ^ (pb_ & 7);
            longx2 v = *(const longx2*)(SH + 16384 + cur * 8192 + pb_ * 128 + sb_ * 16);
            bv[j][0] = v[0]; bv[j][1] = v[1];
        }

        __builtin_amdgcn_s_setprio(1);
        #pragma unroll
        for (int i = 0; i < 4; i++)
            #pragma unroll
            for (int j = 0; j < 4; j++) {
                acc[i][j] = __builtin_amdgcn_mfma_f32_16x16x32_fp8_fp8(av[i][0], bv[j][0], acc[i][j], 0, 0, 0);
                acc[i][j] = __builtin_amdgcn_mfma_f32_16x16x32_fp8_fp8(av[i][1], bv[j][1], acc[i][j], 0, 0, 0);
            }
        __builtin_amdgcn_s_setprio(0);
        __syncthreads();
        cur ^= 1;
    }
#undef STG8

    // ---- epilogue ----
    if (!(vmode == 1 && col0 >= 2048)) {
        #pragma unroll
        for (int i = 0; i < 4; i++) {
            #pragma unroll
            for (int j = 0; j < 4; j++) {
                const long col  = col0 + wc * 64 + j * 16 + l15;
                const int  lrow0 = wr * 64 + i * 16 + lhi * 4;
                const int  lcol  = wc * 64 + j * 16 + l15;
                #pragma unroll
                for (int r = 0; r < 4; r++)
                    SHm[(lrow0 + r) * 128 + lcol] = (bf16_t)(acc[i][j][r] + bias[col]);
            }
        }
        __syncthreads();
        #pragma unroll
        for (int k2 = 0; k2 < 8; k2++) {
            const int cc   = k2 * 256 + tid;
            const int lrow = cc >> 4, lcol = (cc & 15) * 8;
            const long row = row0 + lrow;
            long srow = row;
            if (tperm) {
                const int ri  = (int)row;
                const int bb  = ri / (T_ * HW_);
                const int rem = ri - bb * (T_ * HW_);
                const int tt  = rem / HW_;
                const int hh  = rem - tt * HW_;
                srow = ((long)bb * HW_ + hh) * T_ + tt;
            }
            *(bf16x8*)(Cb + srow * (long)N + col0 + lcol) =
                *(const bf16x8*)&SHm[lrow * 128 + lcol];
        }
        return;
    }

    // vmode=1 V-block: scalar vt path
    #pragma unroll
    for (int i = 0; i < 4; i++) {
        #pragma unroll
        for (int j = 0; j < 4; j++) {
            const long col  = col0 + wc * 64 + j * 16 + l15;
            const long rowb = row0 + wr * 64 + i * 16 + lhi * 4;
            const int hh = ((int)col - 2048) >> 6, d = ((int)col - 2048) & 63;
            const int r0i = (int)rowb;
            const int bt0 = r0i / HW_, hw0 = r0i - bt0 * HW_;
            bf16x4 pk;
            #pragma unroll
            for (int r = 0; r < 4; r++) pk[r] = (bf16_t)(acc[i][j][r] + bias[col]);
            *(bf16x4*)(vout + ((long)(bt0 * 16 + hh) * 64 + d) * HW_ + hw0) = pk;
        }
    }
}

// ---------------------------------------------------------------------------
// Spatial proj GEMM (bf16): repack + fp32 residual.
// ---------------------------------------------------------------------------
__global__ __launch_bounds__(256) void gemm_bt_rpp(const bf16_t* __restrict__ A,
                                                   const bf16_t* __restrict__ BT,
                                                   const float* __restrict__ bias,
                                                   const float* __restrict__ resf,
                                                   bf16_t* __restrict__ Cb,
                                                   int ntx, int M, int N, int K)
{
    __shared__ bf16_t SHm[16384];
#define As_(b) (SHm + (b) * 4096)
#define Bs_(b) (SHm + 8192 + (b) * 4096)
    GEMM_PROLOG_AND_KLOOP(As_, Bs_)

    #pragma unroll
    for (int i = 0; i < 4; i++) {
        #pragma unroll
        for (int j = 0; j < 4; j++) {
            const long col  = col0 + wc * 64 + j * 16 + l15;
            const long rowb = row0 + wr * 64 + i * 16 + lhi * 4;
            const int  lrow0 = wr * 64 + i * 16 + lhi * 4;
            const int  lcol  = wc * 64 + j * 16 + l15;
            #pragma unroll
            for (int r = 0; r < 4; r++)
                SHm[(lrow0 + r) * 128 + lcol] =
                    (bf16_t)(acc[i][j][r] + bias[col] + resf[(rowb + r) * (long)N + col]);
        }
    }
    __syncthreads();
    #pragma unroll
    for (int k2 = 0; k2 < 8; k2++) {
        const int cc   = k2 * 256 + tid;
        const int lrow = cc >> 4, lcol = (cc & 15) * 8;
        *(bf16x8*)(Cb + (row0 + lrow) * (long)N + col0 + lcol) =
            *(const bf16x8*)&SHm[lrow * 128 + lcol];
    }
#undef As_
#undef Bs_
}

// ---------------------------------------------------------------------------
// Final proj GEMM (bf16): fp32 out, bf16 residual; two-pass fp32 repack.
// ---------------------------------------------------------------------------
__global__ __launch_bounds__(256) void gemm_bt_rpo(const bf16_t* __restrict__ A,
                                                   const bf16_t* __restrict__ BT,
                                                   const float* __restrict__ bias,
                                                   const bf16_t* __restrict__ resb,
                                                   float* __restrict__ Cf,
                                                   int ntx, int M, int N, int K)
{
    __shared__ bf16_t SHm[16384];
#define As_(b) (SHm + (b) * 4096)
#define Bs_(b) (SHm + 8192 + (b) * 4096)
    GEMM_PROLOG_AND_KLOOP(As_, Bs_)

    float* SHf = (float*)SHm;                 // 32 KB = 64 rows x 128 fp32
    #pragma unroll
    for (int half = 0; half < 2; half++) {
        if (wr == half) {
            #pragma unroll
            for (int i = 0; i < 4; i++) {
                #pragma unroll
                for (int j = 0; j < 4; j++) {
                    const long col  = col0 + wc * 64 + j * 16 + l15;
                    const long rowb = row0 + wr * 64 + i * 16 + lhi * 4;
                    const int  lrow0 = i * 16 + lhi * 4;
                    const int  lcol  = wc * 64 + j * 16 + l15;
                    #pragma unroll
                    for (int r = 0; r < 4; r++)
                        SHf[(lrow0 + r) * 128 + lcol] =
                            acc[i][j][r] + bias[col]
                            + (float)resb[(rowb + r) * (long)N + col];
                }
            }
        }
        __syncthreads();
        #pragma unroll
        for (int k2 = 0; k2 < 8; k2++) {
            const int cc   = k2 * 256 + tid;       // 0..2047 float4 chunks
            const int lrow = cc >> 5, lc4 = (cc & 31) * 4;
            *(float4*)(Cf + (row0 + half * 64 + lrow) * (long)N + col0 + lc4) =
                *(const float4*)&SHf[lrow * 128 + lc4];
        }
        __syncthreads();
    }
#undef As_
#undef Bs_
}

// ---------------------------------------------------------------------------
// Spatial attention, MFMA flash-style, 192-row Q-tiles, 1-D grid + T1 swizzle.
// exp2-fold with RAW v_exp_f32 (Q pre-scaled by 0.125*log2(e)).
// ---------------------------------------------------------------------------
__global__ __launch_bounds__(256) void attn_spatial(const bf16_t* __restrict__ qkv,
                                                    const bf16_t* __restrict__ vt,
                                                    bf16_t* __restrict__ out)
{
    __shared__ bf16_t Ks[2][64 * 64];
    __shared__ bf16_t Vts[2][64 * 64];
    __shared__ bf16_t Pws[4][16 * 72];
    const int tid = threadIdx.x, lane = tid & 63, w = tid >> 6;
    // bijective XCD swizzle: 1536 blocks, 192 per XCD, g-major groups of 3
    const int bid = blockIdx.x;
    const int wsz = (bid & 7) * 192 + (bid >> 3);
    const int qt = wsz % 3;               // 0..2
    const int g  = wsz / 3;               // 0..511
    const int h  = g & 15, bt = g >> 4;
    const long base = (long)bt * HW_;
    const int l15 = lane & 15, lhi = lane >> 4;
    const int row0 = qt * 192 + w * 16;   // + rg*64

    bf16x8 q[3][2];
    #pragma unroll
    for (int rg = 0; rg < 3; rg++) {
        #pragma unroll
        for (int kk = 0; kk < 2; kk++) {
            bf16x8 tq = *(const bf16x8*)(qkv + (base + row0 + rg * 64 + l15) * D3_
                                         + h * 64 + kk * 32 + lhi * 8);
            #pragma unroll
            for (int e = 0; e < 8; e++)
                tq[e] = (bf16_t)((float)tq[e] * 0.1803368801f);  // 0.125*log2(e)
            q[rg][kk] = tq;
        }
    }

    const bf16_t* Kg = qkv + base * D3_ + 1024 + h * 64;
    const bf16_t* Vg = vt + (long)g * (64 * 576);

#define STAGEKV(kt, bq) do {                                                  \
        _Pragma("unroll")                                                     \
        for (int i_ = 0; i_ < 2; i_++) {                                      \
            const int c_ = i_ * 256 + tid;                                    \
            const int r_ = c_ >> 3, cb_ = (c_ & 7) << 4;                      \
            const int cs_ = cb_ ^ ((r_ & 7) << 4);                            \
            GLDS(Kg + (long)((kt) * 64 + r_) * D3_ + (cs_ >> 1),              \
                 (char*)Ks[bq] + c_ * 16);                                    \
            GLDS(Vg + (long)r_ * 576 + (kt) * 64 + (cs_ >> 1),               \
                 (char*)Vts[bq] + c_ * 16);                                   \
        }                                                                     \
    } while (0)

    float lp[3][4] = {};
    f32x4 o[3][4] = {};

    STAGEKV(0, 0);

    for (int kt = 0; kt < 9; kt++) {
        const int cur = kt & 1;
        __syncthreads();
        if (kt < 8) STAGEKV(kt + 1, cur ^ 1);

        f32x4 acc[3][4] = {};
        #pragma unroll
        for (int j = 0; j < 4; j++) {
            const int key = j * 16 + l15;
            #pragma unroll
            for (int kk = 0; kk < 2; kk++) {
                const int boff = key * 128 + ((kk * 64 + lhi * 16) ^ ((key & 7) << 4));
                bf16x8 kb = *(const bf16x8*)((const char*)Ks[cur] + boff);
                #pragma unroll
                for (int rg = 0; rg < 3; rg++)
                    acc[rg][j] = __builtin_amdgcn_mfma_f32_16x16x32_bf16(q[rg][kk], kb, acc[rg][j], 0, 0, 0);
            }
        }

        #pragma unroll
        for (int rg = 0; rg < 3; rg++) {
            #pragma unroll
            for (int r = 0; r < 4; r++) {
                const float p0 = hw_exp2(acc[rg][0][r]);
                const float p1 = hw_exp2(acc[rg][1][r]);
                const float p2 = hw_exp2(acc[rg][2][r]);
                const float p3 = hw_exp2(acc[rg][3][r]);
                lp[rg][r] += (p0 + p1) + (p2 + p3);
                const int prow = (lhi * 4 + r) * 72 + l15;
                Pws[w][prow]      = (bf16_t)p0;
                Pws[w][prow + 16] = (bf16_t)p1;
                Pws[w][prow + 32] = (bf16_t)p2;
                Pws[w][prow + 48] = (bf16_t)p3;
            }
            __builtin_amdgcn_sched_barrier(0);

            bf16x8 pa[2];
            #pragma unroll
            for (int kk = 0; kk < 2; kk++)
                pa[kk] = *(const bf16x8*)&Pws[w][l15 * 72 + kk * 32 + lhi * 8];
            #pragma unroll
            for (int j = 0; j < 4; j++) {
                const int vrow = j * 16 + l15;
                #pragma unroll
                for (int kk = 0; kk < 2; kk++) {
                    const int boff = vrow * 128 + ((kk * 64 + lhi * 16) ^ ((vrow & 7) << 4));
                    bf16x8 vb = *(const bf16x8*)((const char*)Vts[cur] + boff);
                    o[rg][j] = __builtin_amdgcn_mfma_f32_16x16x32_bf16(pa[kk], vb, o[rg][j], 0, 0, 0);
                }
            }
            __builtin_amdgcn_sched_barrier(0);
        }
    }
#undef STAGEKV

    #pragma unroll
    for (int rg = 0; rg < 3; rg++) {
        #pragma unroll
        for (int r = 0; r < 4; r++) {
            float l = lp[rg][r];
            #pragma unroll
            for (int off = 1; off < 16; off <<= 1) l += __shfl_xor(l, off);
            const float inv = 1.f / l;
            const long row = base + row0 + rg * 64 + lhi * 4 + r;
            #pragma unroll
            for (int j = 0; j < 4; j++)
                out[row * (long)D_ + h * 64 + j * 16 + l15] = (bf16_t)(o[rg][j][r] * inv);
        }
    }
}

// ---------------------------------------------------------------------------
// Temporal attention, MFMA; no-max softmax; in-LDS V transpose (unchanged).
// ---------------------------------------------------------------------------
__global__ __launch_bounds__(256) void attn_temporal(const bf16_t* __restrict__ qkv_t,
                                                     bf16_t* __restrict__ out)
{
    __shared__ bf16_t tile[16 * 1026];     // 32.8 KB; reused as vtt [h*1024+d*16+t]
    __shared__ bf16_t Plds[4][16 * 24];
    const int tid = threadIdx.x, lane = tid & 63, w = tid >> 6;
    const int l15 = lane & 15, lhi = lane >> 4;
    const int bhw = blockIdx.x;            // 0..1151
    const int b = bhw / HW_, hw = bhw % HW_;
    const long base_row = (long)bhw * T_;
    const bf16_t* qrow = qkv_t + (base_row + l15) * D3_;

    #pragma unroll
    for (int it = 0; it < 8; it++) {
        const int c = it * 256 + tid;
        const int row = c >> 7, col = (c & 127) * 8;
        *(bf16x8*)&tile[row * 1026 + col] =
            *(const bf16x8*)(qkv_t + (base_row + row) * D3_ + 2048 + col);
    }
    __syncthreads();
    bf16x8 tv0[4], tv1[4];
    #pragma unroll
    for (int it = 0; it < 4; it++) {
        const int hd = it * 256 + tid;
        #pragma unroll
        for (int t = 0; t < 8; t++) tv0[it][t] = tile[t * 1026 + hd];
        #pragma unroll
        for (int t = 0; t < 8; t++) tv1[it][t] = tile[(8 + t) * 1026 + hd];
    }
    __syncthreads();
    #pragma unroll
    for (int it = 0; it < 4; it++) {
        const int hd = it * 256 + tid;
        *(bf16x8*)&tile[hd * 16]     = tv0[it];
        *(bf16x8*)&tile[hd * 16 + 8] = tv1[it];
    }
    __syncthreads();

    #pragma unroll
    for (int i = 0; i < 4; i++) {
        const int h = w * 4 + i;
        bf16x8 q0 = *(const bf16x8*)(qrow + h * 64 + lhi * 8);
        bf16x8 q1 = *(const bf16x8*)(qrow + h * 64 + 32 + lhi * 8);
        bf16x8 k0 = *(const bf16x8*)(qrow + 1024 + h * 64 + lhi * 8);
        bf16x8 k1 = *(const bf16x8*)(qrow + 1024 + h * 64 + 32 + lhi * 8);
        f32x4 acc = {};
        acc = __builtin_amdgcn_mfma_f32_16x16x32_bf16(q0, k0, acc, 0, 0, 0);
        acc = __builtin_amdgcn_mfma_f32_16x16x32_bf16(q1, k1, acc, 0, 0, 0);

        #pragma unroll
        for (int r = 0; r < 4; r++) {
            const int tq = lhi * 4 + r;
            float p = (l15 <= tq) ? __expf(acc[r] * 0.125f) : 0.f;
            float sum = p;
            #pragma unroll
            for (int off = 1; off < 16; off <<= 1) sum += __shfl_xor(sum, off);
            Plds[w][tq * 24 + l15] = (bf16_t)(p / sum);
        }
        __builtin_amdgcn_sched_barrier(0);

        bf16x8 pa = {};
        if (lhi < 2) pa = *(const bf16x8*)&Plds[w][l15 * 24 + lhi * 8];

        #pragma unroll
        for (int j = 0; j < 4; j++) {
            bf16x8 vb = {};
            if (lhi < 2)
                vb = *(const bf16x8*)&tile[h * 1024 + (j * 16 + l15) * 16 + lhi * 8];
            f32x4 o = {};
            o = __builtin_amdgcn_mfma_f32_16x16x32_bf16(pa, vb, o, 0, 0, 0);
            #pragma unroll
            for (int r = 0; r < 4; r++) {
                const int tq = lhi * 4 + r;
                out[(((long)b * T_ + tq) * HW_ + hw) * D_ + h * 64 + j * 16 + l15] = (bf16_t)o[r];
            }
        }
        __builtin_amdgcn_sched_barrier(0);
    }
}

// ---------------------------------------------------------------------------
extern "C" void kernel_launch(void* const* d_in, const int* in_sizes, int n_in,
                              void* d_out, int out_size, void* d_ws, size_t ws_size,
                              hipStream_t stream)
{
    const float* x       = (const float*)d_in[0];
    const float* ws_qkv  = (const float*)d_in[1];
    const float* bs_qkv  = (const float*)d_in[2];
    const float* ws_proj = (const float*)d_in[3];
    const float* bs_proj = (const float*)d_in[4];
    const float* wt_qkv  = (const float*)d_in[5];
    const float* bt_qkv  = (const float*)d_in[6];
    const float* wt_proj = (const float*)d_in[7];
    const float* bt_proj = (const float*)d_in[8];
    float* out = (float*)d_out;
    (void)in_sizes; (void)n_in; (void)out_size;

    // workspace layout (bytes); region2 is time-multiplexed:
    //   x_f8 (prep..QKV-s) -> att-s (attn_s..proj-s) -> x1_f8 (b2f8..QKV-t)
    //   -> att-t (attn_t..proj-o)
    char* ws = (char*)d_ws;
    bf16_t* qkv   = (bf16_t*)(ws);                  // 113,246,208
    u8*     x_f8  = (u8*)(ws + 113246208L);         // 18,874,368 (in region2)
    bf16_t* att   = (bf16_t*)(ws + 113246208L);     // 37,748,736 (region2)
    u8*     x1_f8 = (u8*)(ws + 113246208L);         // 18,874,368 (in region2)
    bf16_t* x1_bf = (bf16_t*)(ws + 150994944L);     // 37,748,736 (region3)
    bf16_t* vt    = x1_bf;                          // alias: vt dead before x1_bf
    u8*     wTqs8 = (u8*)(ws + 188743680L);         //  3,145,728
    bf16_t* wTps  = (bf16_t*)(ws + 195035136L);     //  2,097,152
    u8*     wTqt8 = (u8*)(ws + 197132288L);         //  3,145,728
    bf16_t* wTpt  = (bf16_t*)(ws + 203423744L);     //  2,097,152
    if (ws_size < 205520896UL) return;              // visible failure: out stays 0

    prep<<<12288, 256, 0, stream>>>(x, x_f8, ws_qkv, wTqs8, ws_proj, wTps,
                                    wt_qkv, wTqt8, wt_proj, wTpt);

    // ---- spatial branch ----  (fp8 QKV; V fused into vt; x1 bf16)
    gemm_f8<<<24 * 144, 256, 0, stream>>>(x_f8, wTqs8, bs_qkv,
                                          qkv, vt, 1, 24,
                                          TOK_, D3_, D_, 0);
    attn_spatial<<<1536, 256, 0, stream>>>(qkv, vt, att);
    gemm_bt_rpp<<<8 * 144, 256, 0, stream>>>(att, wTps, bs_proj, x,
                                             x1_bf, 8, TOK_, D_, D_);
    // ---- temporal branch ----  (x1 -> fp8, fp8 QKV with tperm)
    b2f8<<<4096, 256, 0, stream>>>(x1_bf, x1_f8, (long)TOK_ * D_);
    gemm_f8<<<24 * 144, 256, 0, stream>>>(x1_f8, wTqt8, bt_qkv,
                                          qkv, nullptr, 0, 24,
                                          TOK_, D3_, D_, 1);
    attn_temporal<<<1152, 256, 0, stream>>>(qkv, att);
    gemm_bt_rpo<<<8 * 144, 256, 0, stream>>>(att, wTpt, bt_proj, x1_bf,
                                             out, 8, TOK_, D_, D_);
}